// Round 1
// 770.073 us; speedup vs baseline: 1.0004x; 1.0004x over previous
//
#include <hip/hip_runtime.h>
#include <cmath>

// MLPTexture3D: 16-level hashgrid encode + 32->32->32->4 MLP.
// R4: spatial counting-sort (32^3 bins) ahead of the level-phased encode.
// Encode is bound by random-gather line requests (~0.45 line-req/cyc/CU,
// ILP-neutral), not HBM (8.6%) / VALU (33%). Sorting makes each wave's 64
// points span ~0.03^3 of space so corner lines are shared across lanes at
// levels 0..7 (res<=214): TA same-line coalescing + L1 hits collapse the
// request count there. texc is hoisted out of the 16x per-level recompute.
// Sorted texc lives in d_out (n*16B, rewritten by MLP via out[perm[slot]]).

namespace {
constexpr int kLevels = 16;
constexpr unsigned kTableSize = 1u << 19;
constexpr unsigned kMask = kTableSize - 1u;
constexpr int kCells = 32768;  // 32^3 bins, ~61 pts/cell at N=2M

typedef _Float16 half2_t __attribute__((ext_vector_type(2)));
typedef unsigned int u32;

struct LevelParams {
  float scale[kLevels];
  unsigned res[kLevels];
  int dense[kLevels];
};
}  // namespace

// ---------------- k0: table conversion + weight packing ----------------
__global__ __launch_bounds__(256)
void conv_tables_kernel(const float2* __restrict__ src, half2_t* __restrict__ dst,
                        int n_entries,
                        const float* __restrict__ W1, const float* __restrict__ W2,
                        const float* __restrict__ W3, half2_t* __restrict__ Wh)
{
  int i = blockIdx.x * blockDim.x + threadIdx.x;
  if (i < 512) {
    Wh[i] = half2_t{(_Float16)W1[2 * i], (_Float16)W1[2 * i + 1]};
  } else if (i < 1024) {
    int t = i - 512;
    Wh[512 + t] = half2_t{(_Float16)W2[2 * t], (_Float16)W2[2 * t + 1]};
  } else if (i < 1088) {
    int t = i - 1024;
    Wh[1024 + t] = half2_t{(_Float16)W3[2 * t], (_Float16)W3[2 * t + 1]};
  }
  int stride = gridDim.x * blockDim.x;
  for (; i < n_entries; i += stride) {
    float2 v = src[i];
    dst[i] = half2_t{(_Float16)v.x, (_Float16)v.y};
  }
}

// ---------------- sort passes ----------------
__device__ __forceinline__ void texc_of(const float* __restrict__ pts,
                                        const float* __restrict__ aabb, int i,
                                        float& x, float& y, float& z)
{
  float a0x = aabb[0], a0y = aabb[1], a0z = aabb[2];
  float a1x = aabb[3], a1y = aabb[4], a1z = aabb[5];
  x = fminf(fmaxf((pts[3 * i + 0] - a0x) / (a1x - a0x), 0.f), 1.f);
  y = fminf(fmaxf((pts[3 * i + 1] - a0y) / (a1y - a0y), 0.f), 1.f);
  z = fminf(fmaxf((pts[3 * i + 2] - a0z) / (a1z - a0z), 0.f), 1.f);
}

__device__ __forceinline__ int cell_of(float x, float y, float z)
{
  int cx = min((int)(x * 32.f), 31);
  int cy = min((int)(y * 32.f), 31);
  int cz = min((int)(z * 32.f), 31);
  return cx + (cy << 5) + (cz << 10);
}

__global__ __launch_bounds__(256)
void zero_hist_kernel(u32* __restrict__ hist)
{
  int i = blockIdx.x * blockDim.x + threadIdx.x;
  if (i < kCells) hist[i] = 0u;
}

__global__ __launch_bounds__(256)
void hist_kernel(const float* __restrict__ points, const float* __restrict__ aabb,
                 u32* __restrict__ hist, int n)
{
  int i = blockIdx.x * blockDim.x + threadIdx.x;
  if (i >= n) return;
  float x, y, z;
  texc_of(points, aabb, i, x, y, z);
  atomicAdd(&hist[cell_of(x, y, z)], 1u);
}

// single block, 1024 threads: exclusive scan of 32768 counters
__global__ __launch_bounds__(1024)
void scan_kernel(const u32* __restrict__ hist, u32* __restrict__ cstart)
{
  __shared__ u32 sm[1024];
  int t = threadIdx.x;
  u32 loc[32];
  u32 s = 0;
  #pragma unroll
  for (int k = 0; k < 32; ++k) { loc[k] = hist[t * 32 + k]; s += loc[k]; }
  sm[t] = s;
  __syncthreads();
  u32 v = s;
  for (int off = 1; off < 1024; off <<= 1) {
    u32 a = (t >= off) ? sm[t - off] : 0u;
    __syncthreads();
    v += a;
    sm[t] = v;
    __syncthreads();
  }
  u32 run = v - s;  // exclusive base for this thread's chunk
  #pragma unroll
  for (int k = 0; k < 32; ++k) { cstart[t * 32 + k] = run; run += loc[k]; }
}

__global__ __launch_bounds__(256)
void scatter_kernel(const float* __restrict__ points, const float* __restrict__ aabb,
                    u32* __restrict__ cstart, float4* __restrict__ sorted,
                    u32* __restrict__ perm, int n)
{
  int i = blockIdx.x * blockDim.x + threadIdx.x;
  if (i >= n) return;
  float x, y, z;
  texc_of(points, aabb, i, x, y, z);
  int c = cell_of(x, y, z);
  u32 slot = atomicAdd(&cstart[c], 1u);
  sorted[slot] = float4{x, y, z, 0.f};
  perm[slot] = (u32)i;
}

// ---------------- k1: level-phased encode, widened pair gathers ----------------
__device__ __forceinline__ u32 sel4(uint4 v, u32 j) {
  // v[j] via cndmask tree (no scratch)
  u32 lo = (j & 1u) ? v.y : v.x;
  u32 hi = (j & 1u) ? v.w : v.z;
  return (j & 2u) ? hi : lo;
}

__global__ __launch_bounds__(256)
void encode_kernel(const float4* __restrict__ pts,  // sorted texc
                   const u32* __restrict__ tables,  // fp16x2 entries as u32
                   half2_t* __restrict__ enc,       // [L][N]
                   LevelParams lp, int n, int bpl)
{
  int l = blockIdx.x / bpl;
  int i = (blockIdx.x - l * bpl) * blockDim.x + threadIdx.x;
  if (i >= n) return;

  float4 p = pts[i];
  float x = p.x, y = p.y, z = p.z;

  float s = lp.scale[l];
  unsigned res = lp.res[l];
  bool dense = (lp.dense[l] != 0);
  unsigned rm1 = res - 1u;
  unsigned res2 = res * res;
  const u32* tab = tables + (size_t)l * kTableSize;

  float fx = x * s + 0.5f, fy = y * s + 0.5f, fz = z * s + 0.5f;
  float fx0 = floorf(fx), fy0 = floorf(fy), fz0 = floorf(fz);
  float wx = fx - fx0, wy = fy - fy0, wz = fz - fz0;
  unsigned bx = (unsigned)fx0, by = (unsigned)fy0, bz = (unsigned)fz0;

  unsigned pcx0 = min(bx, rm1), pcx1 = min(bx + 1u, rm1);

  // 4 pairs: p = oy + 2*oz; each pair covers ox=0,1
  u32 idx0[4], idx1[4];
  #pragma unroll
  for (int q = 0; q < 4; ++q) {
    unsigned oy = (unsigned)(q & 1);
    unsigned oz = (unsigned)(q >> 1);
    unsigned pcy = min(by + oy, rm1);
    unsigned pcz = min(bz + oz, rm1);
    if (dense) {
      u32 b = pcy * res + pcz * res2;
      idx0[q] = pcx0 + b;
      idx1[q] = pcx1 + b;
    } else {
      u32 h = (pcy * 2654435761u) ^ (pcz * 805459861u);
      idx0[q] = (pcx0 ^ h) & kMask;
      idx1[q] = (pcx1 ^ h) & kMask;
    }
  }

  // Issue the 4 group loads first (ILP)
  uint4 v[4];
  #pragma unroll
  for (int q = 0; q < 4; ++q)
    v[q] = *reinterpret_cast<const uint4*>(tab + (idx0[q] & ~3u));

  // Masked fix-up loads for corner1 outside the 16B group (~25% of lanes)
  u32 e1x[4] = {0u, 0u, 0u, 0u};
  #pragma unroll
  for (int q = 0; q < 4; ++q) {
    if ((idx0[q] ^ idx1[q]) >= 4u) e1x[q] = tab[idx1[q]];
  }

  float wx1 = wx, wx0 = 1.f - wx;
  float acc0 = 0.f, acc1 = 0.f;
  #pragma unroll
  for (int q = 0; q < 4; ++q) {
    unsigned oy = (unsigned)(q & 1);
    unsigned oz = (unsigned)(q >> 1);
    float wyz = (oy ? wy : 1.f - wy) * (oz ? wz : 1.f - wz);
    u32 e0 = sel4(v[q], idx0[q] & 3u);
    u32 e1g = sel4(v[q], idx1[q] & 3u);
    u32 e1 = ((idx0[q] ^ idx1[q]) < 4u) ? e1g : e1x[q];
    half2_t f0 = __builtin_bit_cast(half2_t, e0);
    half2_t f1 = __builtin_bit_cast(half2_t, e1);
    float w0 = wyz * wx0, w1 = wyz * wx1;
    acc0 += w0 * (float)f0.x + w1 * (float)f1.x;
    acc1 += w0 * (float)f0.y + w1 * (float)f1.y;
  }
  enc[(size_t)l * n + i] = half2_t{(_Float16)acc0, (_Float16)acc1};
}

// ---- legacy (no-sort) encode for the mid workspace tier ----
__global__ __launch_bounds__(256)
void encode_raw_kernel(const float* __restrict__ points,
                       const u32* __restrict__ tables,
                       const float* __restrict__ aabb,
                       half2_t* __restrict__ enc,
                       LevelParams lp, int n, int bpl)
{
  int l = blockIdx.x / bpl;
  int i = (blockIdx.x - l * bpl) * blockDim.x + threadIdx.x;
  if (i >= n) return;
  float x, y, z;
  texc_of(points, aabb, i, x, y, z);

  float s = lp.scale[l];
  unsigned res = lp.res[l];
  bool dense = (lp.dense[l] != 0);
  unsigned rm1 = res - 1u;
  unsigned res2 = res * res;
  const u32* tab = tables + (size_t)l * kTableSize;

  float fx = x * s + 0.5f, fy = y * s + 0.5f, fz = z * s + 0.5f;
  float fx0 = floorf(fx), fy0 = floorf(fy), fz0 = floorf(fz);
  float wx = fx - fx0, wy = fy - fy0, wz = fz - fz0;
  unsigned bx = (unsigned)fx0, by = (unsigned)fy0, bz = (unsigned)fz0;
  unsigned pcx0 = min(bx, rm1), pcx1 = min(bx + 1u, rm1);

  u32 idx0[4], idx1[4];
  #pragma unroll
  for (int q = 0; q < 4; ++q) {
    unsigned oy = (unsigned)(q & 1);
    unsigned oz = (unsigned)(q >> 1);
    unsigned pcy = min(by + oy, rm1);
    unsigned pcz = min(bz + oz, rm1);
    if (dense) {
      u32 b = pcy * res + pcz * res2;
      idx0[q] = pcx0 + b;
      idx1[q] = pcx1 + b;
    } else {
      u32 h = (pcy * 2654435761u) ^ (pcz * 805459861u);
      idx0[q] = (pcx0 ^ h) & kMask;
      idx1[q] = (pcx1 ^ h) & kMask;
    }
  }
  uint4 v[4];
  #pragma unroll
  for (int q = 0; q < 4; ++q)
    v[q] = *reinterpret_cast<const uint4*>(tab + (idx0[q] & ~3u));
  u32 e1x[4] = {0u, 0u, 0u, 0u};
  #pragma unroll
  for (int q = 0; q < 4; ++q) {
    if ((idx0[q] ^ idx1[q]) >= 4u) e1x[q] = tab[idx1[q]];
  }
  float wx1 = wx, wx0 = 1.f - wx;
  float acc0 = 0.f, acc1 = 0.f;
  #pragma unroll
  for (int q = 0; q < 4; ++q) {
    unsigned oy = (unsigned)(q & 1);
    unsigned oz = (unsigned)(q >> 1);
    float wyz = (oy ? wy : 1.f - wy) * (oz ? wz : 1.f - wz);
    u32 e0 = sel4(v[q], idx0[q] & 3u);
    u32 e1g = sel4(v[q], idx1[q] & 3u);
    u32 e1 = ((idx0[q] ^ idx1[q]) < 4u) ? e1g : e1x[q];
    half2_t f0 = __builtin_bit_cast(half2_t, e0);
    half2_t f1 = __builtin_bit_cast(half2_t, e1);
    float w0 = wyz * wx0, w1 = wyz * wx1;
    acc0 += w0 * (float)f0.x + w1 * (float)f1.x;
    acc1 += w0 * (float)f0.y + w1 * (float)f1.y;
  }
  enc[(size_t)l * n + i] = half2_t{(_Float16)acc0, (_Float16)acc1};
}

// ---------------- k2: MLP with fp16 dot2 ----------------
__device__ __forceinline__ float dot2_acc(half2_t a, half2_t b, float c) {
#if __has_builtin(__builtin_amdgcn_fdot2)
  return __builtin_amdgcn_fdot2(a, b, c, false);
#else
  return c + (float)a.x * (float)b.x + (float)a.y * (float)b.y;
#endif
}

__global__ __launch_bounds__(256)
void mlp_kernel(const half2_t* __restrict__ enc,   // [L][N]
                const half2_t* __restrict__ Wh,    // [W1h 512 | W2h 512 | W3h 64]
                const u32* __restrict__ perm,      // slot -> original index (or null)
                float* __restrict__ out, int n)
{
  int i = blockIdx.x * blockDim.x + threadIdx.x;
  if (i >= n) return;

  u32 orig = perm ? perm[i] : (u32)i;  // load early, hide latency

  half2_t e[16];
  #pragma unroll
  for (int l = 0; l < kLevels; ++l) e[l] = enc[(size_t)l * n + i];

  const half2_t* W1h = Wh;
  const half2_t* W2h = Wh + 512;
  const half2_t* W3h = Wh + 1024;

  float h1f[32];
  #pragma unroll
  for (int j = 0; j < 32; ++j) {
    float acc = 0.f;
    #pragma unroll
    for (int k = 0; k < 16; ++k) acc = dot2_acc(e[k], W1h[16 * j + k], acc);
    h1f[j] = fmaxf(acc, 0.f);
  }
  half2_t h1[16];
  #pragma unroll
  for (int k = 0; k < 16; ++k)
    h1[k] = half2_t{(_Float16)h1f[2 * k], (_Float16)h1f[2 * k + 1]};

  float h2f[32];
  #pragma unroll
  for (int j = 0; j < 32; ++j) {
    float acc = 0.f;
    #pragma unroll
    for (int k = 0; k < 16; ++k) acc = dot2_acc(h1[k], W2h[16 * j + k], acc);
    h2f[j] = fmaxf(acc, 0.f);
  }
  half2_t h2[16];
  #pragma unroll
  for (int k = 0; k < 16; ++k)
    h2[k] = half2_t{(_Float16)h2f[2 * k], (_Float16)h2f[2 * k + 1]};

  float o[4];
  #pragma unroll
  for (int j = 0; j < 4; ++j) {
    float acc = 0.f;
    #pragma unroll
    for (int k = 0; k < 16; ++k) acc = dot2_acc(h2[k], W3h[16 * j + k], acc);
    o[j] = acc;
  }

  float4 r;
  r.x = 1.f / (1.f + __expf(-o[0]));
  r.y = 1.f / (1.f + __expf(-o[1]));
  r.z = 1.f / (1.f + __expf(-o[2]));
  r.w = 0.99f / (1.f + __expf(-o[3])) + 0.01f;
  reinterpret_cast<float4*>(out)[orig] = r;
}

// ---------------- fallback: R0 monolithic ----------------
__global__ __launch_bounds__(256)
void hashgrid_mlp_kernel(const float* __restrict__ points,
                         const float* __restrict__ tables,
                         const float* __restrict__ W1,
                         const float* __restrict__ W2,
                         const float* __restrict__ W3,
                         const float* __restrict__ aabb,
                         float* __restrict__ out,
                         LevelParams lp, int n)
{
  int i = blockIdx.x * blockDim.x + threadIdx.x;
  if (i >= n) return;
  float x, y, z;
  texc_of(points, aabb, i, x, y, z);
  float enc[2 * kLevels];
  #pragma unroll
  for (int l = 0; l < kLevels; ++l) {
    float s = lp.scale[l];
    unsigned res = lp.res[l];
    bool dense = (lp.dense[l] != 0);
    unsigned rm1 = res - 1u;
    unsigned res2 = res * res;
    float fx = x * s + 0.5f, fy = y * s + 0.5f, fz = z * s + 0.5f;
    float fx0 = floorf(fx), fy0 = floorf(fy), fz0 = floorf(fz);
    float wx = fx - fx0, wy = fy - fy0, wz = fz - fz0;
    unsigned bx = (unsigned)fx0, by = (unsigned)fy0, bz = (unsigned)fz0;
    const float2* tab = reinterpret_cast<const float2*>(tables) + (size_t)l * kTableSize;
    float acc0 = 0.f, acc1 = 0.f;
    #pragma unroll
    for (int c = 0; c < 8; ++c) {
      unsigned ox = (unsigned)(c & 1);
      unsigned oy = (unsigned)((c >> 1) & 1);
      unsigned oz = (unsigned)((c >> 2) & 1);
      unsigned pcx = min(bx + ox, rm1);
      unsigned pcy = min(by + oy, rm1);
      unsigned pcz = min(bz + oz, rm1);
      unsigned idx;
      if (dense) idx = pcx + pcy * res + pcz * res2;
      else idx = (pcx ^ (pcy * 2654435761u) ^ (pcz * 805459861u)) & kMask;
      float wt = (ox ? wx : 1.f - wx) * (oy ? wy : 1.f - wy) * (oz ? wz : 1.f - wz);
      float2 f = tab[idx];
      acc0 += wt * f.x;
      acc1 += wt * f.y;
    }
    enc[2 * l + 0] = acc0;
    enc[2 * l + 1] = acc1;
  }
  float h1[32];
  #pragma unroll
  for (int j = 0; j < 32; ++j) {
    float acc = 0.f;
    #pragma unroll
    for (int k = 0; k < 32; ++k) acc += enc[k] * W1[32 * j + k];
    h1[j] = fmaxf(acc, 0.f);
  }
  float h2[32];
  #pragma unroll
  for (int j = 0; j < 32; ++j) {
    float acc = 0.f;
    #pragma unroll
    for (int k = 0; k < 32; ++k) acc += h1[k] * W2[32 * j + k];
    h2[j] = fmaxf(acc, 0.f);
  }
  float o[4];
  #pragma unroll
  for (int j = 0; j < 4; ++j) {
    float acc = 0.f;
    #pragma unroll
    for (int k = 0; k < 32; ++k) acc += h2[k] * W3[32 * j + k];
    o[j] = acc;
  }
  float4 r;
  r.x = 1.f / (1.f + __expf(-o[0]));
  r.y = 1.f / (1.f + __expf(-o[1]));
  r.z = 1.f / (1.f + __expf(-o[2]));
  r.w = 0.99f / (1.f + __expf(-o[3])) + 0.01f;
  reinterpret_cast<float4*>(out)[i] = r;
}

extern "C" void kernel_launch(void* const* d_in, const int* in_sizes, int n_in,
                              void* d_out, int out_size, void* d_ws, size_t ws_size,
                              hipStream_t stream) {
  const float* points = (const float*)d_in[0];
  const float* tables = (const float*)d_in[1];
  const float* W1     = (const float*)d_in[2];
  const float* W2     = (const float*)d_in[3];
  const float* W3     = (const float*)d_in[4];
  const float* aabb   = (const float*)d_in[5];
  float* out = (float*)d_out;
  int n = in_sizes[0] / 3;

  LevelParams lp;
  const double pls = std::exp(std::log(4096.0 / 16.0) / 15.0);
  for (int l = 0; l < kLevels; ++l) {
    double s = 16.0 * std::pow(pls, (double)l) - 1.0;
    lp.scale[l] = (float)s;
    long long res = (long long)std::ceil(s) + 1;
    lp.res[l] = (unsigned)res;
    lp.dense[l] = (res * res * res <= (long long)kTableSize) ? 1 : 0;
  }

  const int block = 256;
  const int n_entries = kLevels * (int)kTableSize;
  const size_t tab_f16_bytes = (size_t)kLevels * kTableSize * sizeof(half2_t);  // 32 MB
  const size_t enc_bytes     = (size_t)kLevels * (size_t)n * sizeof(half2_t);   // 128 MB
  const size_t w_bytes       = 1088 * sizeof(half2_t);
  const size_t perm_bytes    = (size_t)n * sizeof(u32);                          // 8 MB
  const size_t hist_bytes    = (size_t)kCells * sizeof(u32);                     // 128 KB

  const size_t need_old    = tab_f16_bytes + enc_bytes + w_bytes;
  const size_t need_sorted = need_old + perm_bytes + 2 * hist_bytes;
  const bool out_fits_sorted = (size_t)out_size >= (size_t)n * sizeof(float4);

  const int grid_n = (n + block - 1) / block;
  const int bpl = grid_n;

  if (ws_size >= need_sorted && out_fits_sorted) {
    char* p = (char*)d_ws;
    half2_t* tab_f16 = (half2_t*)p;               p += tab_f16_bytes;
    half2_t* enc     = (half2_t*)p;               p += enc_bytes;
    u32*     perm    = (u32*)p;                   p += perm_bytes;
    u32*     hist    = (u32*)p;                   p += hist_bytes;
    u32*     cstart  = (u32*)p;                   p += hist_bytes;
    half2_t* Wh      = (half2_t*)p;
    float4*  sorted  = (float4*)d_out;            // scratch; MLP fully rewrites out

    conv_tables_kernel<<<2048, block, 0, stream>>>(
        reinterpret_cast<const float2*>(tables), tab_f16, n_entries, W1, W2, W3, Wh);
    zero_hist_kernel<<<(kCells + block - 1) / block, block, 0, stream>>>(hist);
    hist_kernel<<<grid_n, block, 0, stream>>>(points, aabb, hist, n);
    scan_kernel<<<1, 1024, 0, stream>>>(hist, cstart);
    scatter_kernel<<<grid_n, block, 0, stream>>>(points, aabb, cstart, sorted, perm, n);
    encode_kernel<<<bpl * kLevels, block, 0, stream>>>(
        sorted, reinterpret_cast<const u32*>(tab_f16), enc, lp, n, bpl);
    mlp_kernel<<<grid_n, block, 0, stream>>>(enc, Wh, perm, out, n);
  } else if (ws_size >= need_old) {
    half2_t* tab_f16 = reinterpret_cast<half2_t*>(d_ws);
    half2_t* enc = reinterpret_cast<half2_t*>((char*)d_ws + tab_f16_bytes);
    half2_t* Wh  = reinterpret_cast<half2_t*>((char*)d_ws + tab_f16_bytes + enc_bytes);

    conv_tables_kernel<<<2048, block, 0, stream>>>(
        reinterpret_cast<const float2*>(tables), tab_f16, n_entries, W1, W2, W3, Wh);
    encode_raw_kernel<<<bpl * kLevels, block, 0, stream>>>(
        points, reinterpret_cast<const u32*>(tab_f16), aabb, enc, lp, n, bpl);
    mlp_kernel<<<grid_n, block, 0, stream>>>(enc, Wh, nullptr, out, n);
  } else {
    hashgrid_mlp_kernel<<<grid_n, block, 0, stream>>>(
        points, tables, W1, W2, W3, aabb, out, lp, n);
  }
}